// Round 1
// baseline (13249.043 us; speedup 1.0000x reference)
//
#include <hip/hip_runtime.h>
#include <math.h>

#define MAX_LEN 128
#define NSYM    32000
#define HID     1024
#define BATCH   32

// ---------------------------------------------------------------------------
// Workspace layout (d_ws):
//   float              h_buf[2][BATCH][HID]        256 KB  (ping-pong hidden state)
//   unsigned long long slots[MAX_LEN][BATCH]        32 KB  (packed argmax per step)
// d_ws is poisoned 0xAA before every launch -> init_slots zeroes slots each call.
// h_buf needs no init: written (step t) before read (step t / t+1).
// ---------------------------------------------------------------------------

__device__ __forceinline__ unsigned fkey(float x) {
    unsigned u = __float_as_uint(x);
    return (u & 0x80000000u) ? ~u : (u | 0x80000000u);  // monotonic float->uint
}

__global__ void init_slots(unsigned long long* slots) {
    int i = blockIdx.x * blockDim.x + threadIdx.x;
    if (i < MAX_LEN * BATCH) slots[i] = 0ULL;
}

// ---------------------------------------------------------------------------
// GRU gate kernel: one step.  grid = 256 blocks x 256 threads.
// Block owns 4 h-columns (j0..j0+3): stages 24 w-rows (w_ih/w_hh x {r,z,n} x 4j)
// plus x-rows (emb gather) and h-rows in LDS, k-chunks of 128.
// Thread t: pair = t&127 -> (b = pair&31, jj = pair>>5), half = t>>7
//   half 0: 3 dots of x against w_ih rows; half 1: 3 dots of h against w_hh.
// Gates fused in-block at the end -> h_next.
// ---------------------------------------------------------------------------
__global__ __launch_bounds__(256) void gru_step(
    const float* __restrict__ h_in,      // d_in h (used at t==0)
    const float* __restrict__ w_ih,
    const float* __restrict__ w_hh,
    const float* __restrict__ b_ih,
    const float* __restrict__ b_hh,
    const float* __restrict__ emb,
    const float* __restrict__ h_prev,    // h_buf[(t+1)&1] (valid t>0)
    float* __restrict__ h_next,          // h_buf[t&1]
    const unsigned long long* __restrict__ slot_prev,  // slots[t-1] (valid t>0)
    int t)
{
    __shared__ float a_t[2][BATCH][129];   // [half][b][k] pad-129: conflict-free reads
    __shared__ float w_t[24][128];         // [12*half + 4*g + jj][k]
    __shared__ float s_gh[128][3];
    __shared__ int   s_tok[BATCH];

    const int tid  = threadIdx.x;
    const int pair = tid & 127;
    const int half = tid >> 7;
    const int b    = pair & 31;
    const int jj   = pair >> 5;
    const int j0   = blockIdx.x * 4;

    if (tid < BATCH) {
        int tok;
        if (t == 0) tok = NSYM;  // BOS row
        else {
            unsigned long long s = slot_prev[tid];
            tok = (int)(0xFFFFFFFFu - (unsigned)(s & 0xFFFFFFFFull));
        }
        s_tok[tid] = tok;
    }
    __syncthreads();

    const float* hp = (t == 0) ? h_in : h_prev;

    float acc0 = 0.f, acc1 = 0.f, acc2 = 0.f;

    float4 pw[3], pa[8];

    // prefetch chunk 0 (global -> regs)
    {
        const int k0 = 0;
        #pragma unroll
        for (int i = 0; i < 3; ++i) {
            int f = tid + 256 * i;            // 0..767
            int r = f >> 5, kq = f & 31;
            int rh = r / 12, rem = r % 12, g = rem >> 2, jx = rem & 3;
            const float* wsrc = rh ? w_hh : w_ih;
            size_t row = (size_t)(j0 + jx + 1024 * g);
            pw[i] = *(const float4*)&wsrc[row * HID + k0 + 4 * kq];
        }
        #pragma unroll
        for (int i = 0; i < 8; ++i) {
            int f = tid + 256 * i;            // 0..2047
            int hh = f >> 10, bb = (f >> 5) & 31, kq = f & 31;
            const float* src = (hh == 0) ? &emb[(size_t)s_tok[bb] * HID]
                                         : &hp[(size_t)bb * HID];
            pa[i] = *(const float4*)&src[k0 + 4 * kq];
        }
    }

    const float* ar = &a_t[half][b][0];
    const float* w0 = &w_t[half * 12 + 0 + jj][0];
    const float* w1 = &w_t[half * 12 + 4 + jj][0];
    const float* w2 = &w_t[half * 12 + 8 + jj][0];

    for (int c = 0; c < 8; ++c) {
        __syncthreads();  // previous chunk's compute done
        // regs -> LDS
        #pragma unroll
        for (int i = 0; i < 3; ++i) {
            int f = tid + 256 * i;
            int r = f >> 5, kq = f & 31;
            *(float4*)&w_t[r][4 * kq] = pw[i];
        }
        #pragma unroll
        for (int i = 0; i < 8; ++i) {
            int f = tid + 256 * i;
            int hh = f >> 10, bb = (f >> 5) & 31, kq = f & 31;
            float* dst = &a_t[hh][bb][4 * kq];
            dst[0] = pa[i].x; dst[1] = pa[i].y; dst[2] = pa[i].z; dst[3] = pa[i].w;
        }
        __syncthreads();  // LDS ready

        if (c + 1 < 8) {
            const int k0 = (c + 1) * 128;
            #pragma unroll
            for (int i = 0; i < 3; ++i) {
                int f = tid + 256 * i;
                int r = f >> 5, kq = f & 31;
                int rh = r / 12, rem = r % 12, g = rem >> 2, jx = rem & 3;
                const float* wsrc = rh ? w_hh : w_ih;
                size_t row = (size_t)(j0 + jx + 1024 * g);
                pw[i] = *(const float4*)&wsrc[row * HID + k0 + 4 * kq];
            }
            #pragma unroll
            for (int i = 0; i < 8; ++i) {
                int f = tid + 256 * i;
                int hh = f >> 10, bb = (f >> 5) & 31, kq = f & 31;
                const float* src = (hh == 0) ? &emb[(size_t)s_tok[bb] * HID]
                                             : &hp[(size_t)bb * HID];
                pa[i] = *(const float4*)&src[k0 + 4 * kq];
            }
        }

        #pragma unroll 16
        for (int kk = 0; kk < 128; ++kk) {
            float av = ar[kk];
            acc0 = fmaf(av, w0[kk], acc0);
            acc1 = fmaf(av, w1[kk], acc1);
            acc2 = fmaf(av, w2[kk], acc2);
        }
    }

    __syncthreads();
    if (half == 1) {
        s_gh[pair][0] = acc0; s_gh[pair][1] = acc1; s_gh[pair][2] = acc2;
    }
    __syncthreads();
    if (half == 0) {
        int j = j0 + jj;
        float gir = acc0 + b_ih[j];
        float giz = acc1 + b_ih[j + 1024];
        float gin = acc2 + b_ih[j + 2048];
        float ghr = s_gh[pair][0] + b_hh[j];
        float ghz = s_gh[pair][1] + b_hh[j + 1024];
        float ghn = s_gh[pair][2] + b_hh[j + 2048];
        float r = 1.f / (1.f + expf(-(gir + ghr)));
        float z = 1.f / (1.f + expf(-(giz + ghz)));
        float n = tanhf(gin + r * ghn);
        float hv = hp[(size_t)b * HID + j];
        h_next[(size_t)b * HID + j] = (1.f - z) * n + z * hv;
    }
}

// ---------------------------------------------------------------------------
// Classifier kernel: logits tile + fused argmax.  grid = 250 blocks x 256 thr.
// Block: 32b x 128v tile, k-chunks of 64 in LDS (pad-65), reg-prefetch dbuf.
// Thread (tx = t&31, ty = t>>5): 4b x 4v register tile, v strided by 32
// (strided v keeps LDS reads conflict-free and global writes coalesced).
// ---------------------------------------------------------------------------
__global__ __launch_bounds__(256) void cls_step(
    const float* __restrict__ h_cur,     // h_buf[t&1]
    const float* __restrict__ cls_w,
    const float* __restrict__ cls_b,
    float* __restrict__ out_t,           // d_out + t*BATCH*NSYM
    unsigned long long* __restrict__ slot_t)  // slots + t*BATCH
{
    __shared__ float w_t[128][65];       // [v][k] pad-65
    __shared__ float a_t[BATCH][65];     // [b][k] pad-65
    __shared__ unsigned long long s_best[BATCH];

    const int tid = threadIdx.x;
    const int tx  = tid & 31;
    const int ty  = tid >> 5;            // 0..7
    const int v0  = blockIdx.x * 128;

    if (tid < BATCH) s_best[tid] = 0ULL;

    float acc[4][4];
    #pragma unroll
    for (int i = 0; i < 4; ++i)
        #pragma unroll
        for (int m = 0; m < 4; ++m) acc[i][m] = 0.f;

    float4 pw[8], pa[2];

    // prefetch chunk 0
    {
        const int k0 = 0;
        #pragma unroll
        for (int i = 0; i < 8; ++i) {
            int f = tid + 256 * i;        // 0..2047
            int v = f >> 4, kq = f & 15;
            pw[i] = *(const float4*)&cls_w[(size_t)(v0 + v) * HID + k0 + 4 * kq];
        }
        #pragma unroll
        for (int i = 0; i < 2; ++i) {
            int f = tid + 256 * i;        // 0..511
            int bb = f >> 4, kq = f & 15;
            pa[i] = *(const float4*)&h_cur[(size_t)bb * HID + k0 + 4 * kq];
        }
    }

    for (int c = 0; c < 16; ++c) {
        __syncthreads();
        #pragma unroll
        for (int i = 0; i < 8; ++i) {
            int f = tid + 256 * i;
            int v = f >> 4, kq = f & 15;
            float* dst = &w_t[v][4 * kq];
            dst[0] = pw[i].x; dst[1] = pw[i].y; dst[2] = pw[i].z; dst[3] = pw[i].w;
        }
        #pragma unroll
        for (int i = 0; i < 2; ++i) {
            int f = tid + 256 * i;
            int bb = f >> 4, kq = f & 15;
            float* dst = &a_t[bb][4 * kq];
            dst[0] = pa[i].x; dst[1] = pa[i].y; dst[2] = pa[i].z; dst[3] = pa[i].w;
        }
        __syncthreads();

        if (c + 1 < 16) {
            const int k0 = (c + 1) * 64;
            #pragma unroll
            for (int i = 0; i < 8; ++i) {
                int f = tid + 256 * i;
                int v = f >> 4, kq = f & 15;
                pw[i] = *(const float4*)&cls_w[(size_t)(v0 + v) * HID + k0 + 4 * kq];
            }
            #pragma unroll
            for (int i = 0; i < 2; ++i) {
                int f = tid + 256 * i;
                int bb = f >> 4, kq = f & 15;
                pa[i] = *(const float4*)&h_cur[(size_t)bb * HID + k0 + 4 * kq];
            }
        }

        #pragma unroll 8
        for (int kk = 0; kk < 64; ++kk) {
            float av[4], wv[4];
            #pragma unroll
            for (int i = 0; i < 4; ++i) av[i] = a_t[4 * ty + i][kk];
            #pragma unroll
            for (int m = 0; m < 4; ++m) wv[m] = w_t[tx + 32 * m][kk];
            #pragma unroll
            for (int i = 0; i < 4; ++i)
                #pragma unroll
                for (int m = 0; m < 4; ++m)
                    acc[i][m] = fmaf(av[i], wv[m], acc[i][m]);
        }
    }

    // epilogue: bias, store logits, fused argmax
    float cb[4];
    #pragma unroll
    for (int m = 0; m < 4; ++m) cb[m] = cls_b[v0 + tx + 32 * m];

    #pragma unroll
    for (int i = 0; i < 4; ++i) {
        int b = 4 * ty + i;
        unsigned long long best = 0ULL;
        #pragma unroll
        for (int m = 0; m < 4; ++m) {
            int v = v0 + tx + 32 * m;
            float val = acc[i][m] + cb[m];
            out_t[(size_t)b * NSYM + v] = val;
            unsigned long long pk =
                ((unsigned long long)fkey(val) << 32) |
                (unsigned long long)(0xFFFFFFFFu - (unsigned)v);
            if (pk > best) best = pk;
        }
        atomicMax(&s_best[b], best);
    }
    __syncthreads();
    if (tid < BATCH) atomicMax(&slot_t[tid], s_best[tid]);
}

// ---------------------------------------------------------------------------
extern "C" void kernel_launch(void* const* d_in, const int* in_sizes, int n_in,
                              void* d_out, int out_size, void* d_ws, size_t ws_size,
                              hipStream_t stream) {
    const float* h0    = (const float*)d_in[0];
    const float* w_ih  = (const float*)d_in[1];
    const float* w_hh  = (const float*)d_in[2];
    const float* b_ih  = (const float*)d_in[3];
    const float* b_hh  = (const float*)d_in[4];
    const float* cls_w = (const float*)d_in[5];
    const float* cls_b = (const float*)d_in[6];
    const float* emb   = (const float*)d_in[7];
    float* out = (float*)d_out;

    float* h_buf = (float*)d_ws;  // 2 * BATCH * HID floats
    unsigned long long* slots =
        (unsigned long long*)((char*)d_ws + (size_t)2 * BATCH * HID * sizeof(float));

    init_slots<<<16, 256, 0, stream>>>(slots);

    for (int t = 0; t < MAX_LEN; ++t) {
        float* h_prev = h_buf + (size_t)((t + 1) & 1) * BATCH * HID;
        float* h_next = h_buf + (size_t)(t & 1) * BATCH * HID;
        const unsigned long long* slot_prev = slots + (size_t)(t > 0 ? (t - 1) : 0) * BATCH;

        gru_step<<<256, 256, 0, stream>>>(h0, w_ih, w_hh, b_ih, b_hh, emb,
                                          h_prev, h_next, slot_prev, t);
        cls_step<<<250, 256, 0, stream>>>(h_next, cls_w, cls_b,
                                          out + (size_t)t * BATCH * NSYM,
                                          slots + (size_t)t * BATCH);
    }
}